// Round 19
// baseline (318.875 us; speedup 1.0000x reference)
//
#include <hip/hip_runtime.h>
#include <hip/hip_fp16.h>
#include <math.h>

#define NN 100000
#define EE 1600000
#define ET (EE + NN)
#define BWN 64        // nodes per bucket
#define NBUCK 1563    // ceil(NN/BWN)
#define ACHUNK 4096   // edges per bucket-scatter block
#define NAB 416       // ceil(ET/ACHUNK)
#define MAXS 1792     // LDS staging cap (mean 1088, sd ~33 -> +21 sigma)

typedef _Float16 f16x8 __attribute__((ext_vector_type(8)));
typedef float f32x4 __attribute__((ext_vector_type(4)));
typedef float f32x2 __attribute__((ext_vector_type(2)));

__device__ __forceinline__ float lrelu(float x) { return x > 0.f ? x : 0.2f * x; }

// ---- W1 fragment pack (single plane fp16) -----------------------------------------
__global__ void k_w1pack(const float* __restrict__ W1, __half* __restrict__ w1p) {
    int idx = blockIdx.x * 256 + threadIdx.x;   // 0..16383
    int j = idx & 7, lane = (idx >> 3) & 63, k0 = (idx >> 9) & 3;
    int ct = (idx >> 11) & 7;
    int k = k0 * 32 + (lane >> 4) * 8 + j;
    int c = ct * 16 + (lane & 15);
    _Float16 v = (_Float16)W1[k * 128 + c];
    w1p[idx] = *(__half*)&v;
}

// ---- Layer 1 GEMM via MFMA (fp16), swapped operands; fp8 h1; es/ed from fp32 acc --
__global__ __launch_bounds__(256) void k_gemm1(
        const float* __restrict__ x, const __half* __restrict__ w1p,
        const float* __restrict__ as1, const float* __restrict__ ad1,
        unsigned* __restrict__ h1b, float* __restrict__ es1, float* __restrict__ ed1) {
    int tid = threadIdx.x;
    int w = tid >> 6, lane = tid & 63;
    int rb = blockIdx.x * 64 + w * 16;
    int l15 = lane & 15, rg = lane >> 4;

    int arow = rb + l15;
    bool aok = arow < NN;
    const float4* x4 = (const float4*)x;
    f16x8 ah[4];
    #pragma unroll
    for (int k0 = 0; k0 < 4; ++k0) {
        float4 p0 = make_float4(0.f, 0.f, 0.f, 0.f), p1 = p0;
        if (aok) {
            int fi = arow * 32 + k0 * 8 + rg * 2;
            p0 = x4[fi];
            p1 = x4[fi + 1];
        }
        float pv[8] = {p0.x, p0.y, p0.z, p0.w, p1.x, p1.y, p1.z, p1.w};
        #pragma unroll
        for (int j = 0; j < 8; ++j) ah[k0][j] = (_Float16)pv[j];
    }

    const f16x8* w1f = (const f16x8*)w1p;   // [ct:8][k0:4][lane:64]
    f32x4 acc[8];
    #pragma unroll
    for (int ct = 0; ct < 8; ++ct) acc[ct] = (f32x4){0.f, 0.f, 0.f, 0.f};
    #pragma unroll
    for (int ct = 0; ct < 8; ++ct) {
        #pragma unroll
        for (int k0 = 0; k0 < 4; ++k0) {
            f16x8 bh = w1f[(ct * 4 + k0) * 64 + lane];
            acc[ct] = __builtin_amdgcn_mfma_f32_16x16x32_f16(bh, ah[k0], acc[ct], 0, 0, 0);
        }
    }

    int row = rb + l15;
    bool rok = row < NN;
    #pragma unroll
    for (int ct = 0; ct < 8; ++ct) {
        if (rok) {
            unsigned pw = __builtin_amdgcn_cvt_pk_fp8_f32(acc[ct][0], acc[ct][1], 0u, false);
            pw = __builtin_amdgcn_cvt_pk_fp8_f32(acc[ct][2], acc[ct][3], pw, true);
            h1b[row * 32 + ct * 4 + rg] = pw;
        }
        float4 a4 = ((const float4*)as1)[ct * 4 + rg];
        float4 d4 = ((const float4*)ad1)[ct * 4 + rg];
        float s = acc[ct][0] * a4.x + acc[ct][1] * a4.y + acc[ct][2] * a4.z + acc[ct][3] * a4.w;
        float d = acc[ct][0] * d4.x + acc[ct][1] * d4.y + acc[ct][2] * d4.z + acc[ct][3] * d4.w;
        s += __shfl_xor(s, 16); s += __shfl_xor(s, 32);
        d += __shfl_xor(d, 16); d += __shfl_xor(d, 32);
        if (rg == 0 && rok) { es1[row * 8 + ct] = s; ed1[row * 8 + ct] = d; }
    }
}

// ================= CSR build: two-level bucket sort (write-amp-free) ===============
__global__ void k_bhist(const int* __restrict__ dst, int* __restrict__ bcnt) {
    __shared__ int lh[NBUCK];
    int t = threadIdx.x;
    for (int i = t; i < NBUCK; i += 256) lh[i] = 0;
    __syncthreads();
    int c0 = blockIdx.x * ACHUNK;
    #pragma unroll
    for (int i = 0; i < 16; ++i) {
        int e = c0 + t + i * 256;
        if (e < ET) {
            int d = (e < EE) ? dst[e] : e - EE;
            atomicAdd(&lh[d >> 6], 1);
        }
    }
    __syncthreads();
    for (int i = t; i < NBUCK; i += 256) {
        int c = lh[i];
        if (c) atomicAdd(&bcnt[i], c);
    }
}

// single block, 8 buckets per thread (2048 >= NBUCK+1)
__global__ void k_bscan(const int* __restrict__ bcnt, int* __restrict__ bbase,
                        int* __restrict__ bcur) {
    __shared__ int sd[256];
    int t = threadIdx.x;
    int base = t * 8;
    int v[8];
    int s = 0;
    #pragma unroll
    for (int j = 0; j < 8; ++j) {
        int i = base + j;
        v[j] = (i < NBUCK) ? bcnt[i] : 0;
        s += v[j];
    }
    sd[t] = s;
    __syncthreads();
    for (int off = 1; off < 256; off <<= 1) {
        int x = (t >= off) ? sd[t - off] : 0;
        __syncthreads();
        sd[t] += x;
        __syncthreads();
    }
    int excl = sd[t] - s;
    #pragma unroll
    for (int j = 0; j < 8; ++j) {
        int i = base + j;
        if (i <= NBUCK) { bbase[i] = excl; if (i < NBUCK) bcur[i] = excl; }
        excl += v[j];
    }
}

__global__ void k_bscatter(const int* __restrict__ src, const int* __restrict__ dst,
                           int* __restrict__ bcur, unsigned int* __restrict__ bedge) {
    __shared__ int lh[NBUCK];
    __shared__ int lb[NBUCK];
    int t = threadIdx.x;
    for (int i = t; i < NBUCK; i += 256) lh[i] = 0;
    __syncthreads();
    int c0 = blockIdx.x * ACHUNK;
    unsigned int val[16];
    int bkt[16];
    int rnk[16];
    #pragma unroll
    for (int i = 0; i < 16; ++i) {
        int e = c0 + t + i * 256;
        if (e < ET) {
            int s, d;
            if (e < EE) { s = src[e]; d = dst[e]; } else { s = d = e - EE; }
            int b = d >> 6;
            bkt[i] = b;
            val[i] = (unsigned)s | ((unsigned)(d & 63) << 24);
            rnk[i] = atomicAdd(&lh[b], 1);
        } else bkt[i] = -1;
    }
    __syncthreads();
    for (int i = t; i < NBUCK; i += 256) {
        int c = lh[i];
        lb[i] = c ? atomicAdd(&bcur[i], c) : 0;
    }
    __syncthreads();
    #pragma unroll
    for (int i = 0; i < 16; ++i)
        if (bkt[i] >= 0) bedge[lb[bkt[i]] + rnk[i]] = val[i];
}

// --- Fused: rp (wave-shfl scan); place + per-node value sort (determinism) +
//     coalesced col write. 64-node buckets. --------------------------------------
__global__ void k_place(const unsigned int* __restrict__ bedge,
                        const int* __restrict__ bbase, int* __restrict__ rp,
                        int* __restrict__ col) {
    __shared__ int lh[BWN];
    __shared__ int ex[BWN + 1];
    __shared__ int lcur[BWN];
    __shared__ int stg[MAXS];
    int b = blockIdx.x, t = threadIdx.x;
    int beg = bbase[b], end = bbase[b + 1];
    if (t < BWN) { lh[t] = 0; lcur[t] = 0; }
    __syncthreads();
    for (int e = beg + t; e < end; e += 256) atomicAdd(&lh[(bedge[e] >> 24) & 63], 1);
    __syncthreads();
    if (t < 64) {
        int v = lh[t];
        int x = v;
        #pragma unroll
        for (int off = 1; off < 64; off <<= 1) {
            int y = __shfl_up(x, off);
            if (t >= off) x += y;
        }
        ex[t] = x - v;
        if (t == 63) ex[64] = x;
    }
    __syncthreads();
    int n = b * BWN + t;
    if (t < BWN && n < NN) rp[n] = beg + ex[t];
    if (b == 0 && t == 0) rp[NN] = ET;
    int S = ex[BWN];
    int lane = t & 63, w = t >> 6;
    if (S <= MAXS) {
        for (int e = beg + t; e < end; e += 256) {
            unsigned u = bedge[e];
            int i = (u >> 24) & 63;
            int pos = ex[i] + atomicAdd(&lcur[i], 1);
            stg[pos] = (int)(u & 0xFFFFFFu);
        }
        __syncthreads();
        for (int i = w; i < BWN; i += 4) {
            int sb = ex[i], d = lh[i];
            if (d <= 1) continue;
            if (d <= 64) {
                int vv = (lane < d) ? stg[sb + lane] : 0x7fffffff;
                #pragma unroll
                for (int k = 2; k <= 64; k <<= 1) {
                    #pragma unroll
                    for (int j = k >> 1; j > 0; j >>= 1) {
                        int other = __shfl_xor(vv, j);
                        bool lower = (lane & j) == 0;
                        bool up = (lane & k) == 0;
                        vv = (lower == up) ? min(vv, other) : max(vv, other);
                    }
                }
                if (lane < d) stg[sb + lane] = vv;
            } else if (lane == 0) {
                for (int p = sb + 1; p < sb + d; ++p) {
                    int key = stg[p]; int j = p - 1;
                    while (j >= sb && stg[j] > key) { stg[j + 1] = stg[j]; --j; }
                    stg[j + 1] = key;
                }
            }
        }
        __syncthreads();
        for (int j = t; j < S; j += 256) col[beg + j] = stg[j];
    } else {
        for (int e = beg + t; e < end; e += 256) {
            unsigned u = bedge[e];
            int i = (u >> 24) & 63;
            int pos = beg + ex[i] + atomicAdd(&lcur[i], 1);
            col[pos] = (int)(u & 0xFFFFFFu);
        }
        __syncthreads();
        if (t < BWN) {
            int sb = beg + ex[t], d = lh[t];
            for (int p = sb + 1; p < sb + d; ++p) {
                int key = col[p]; int j = p - 1;
                while (j >= sb && col[j] > key) { col[j + 1] = col[j]; --j; }
                col[j + 1] = key;
            }
        }
    }
}

// --- Layer 1 aggregate FUSED with layer-2 GEMM + logits2.
//     8 lanes/node, fp8 h1 gather, 2-edge unroll; epilogue computes the full
//     out1 row in-register, then h2 = row @ W2 (W2 staged in LDS, pad 41),
//     butterfly-reduces over the 8-lane group, emits h2h + es2/ed2 directly.
//     Eliminates the out1 tensor and the separate gemm2 kernel; the added VALU
//     work hides under the gather latency (VALUBusy was 38%). ----------------------
__global__ __launch_bounds__(256) void k_agg1(
        const int* __restrict__ rp, const int* __restrict__ col,
        const uint4* __restrict__ h1v, const float* __restrict__ es1,
        const float* __restrict__ ed1, const float* __restrict__ b1,
        const float* __restrict__ W2, const float* __restrict__ as2,
        const float* __restrict__ ad2, __half* __restrict__ h2h,
        float* __restrict__ es2, float* __restrict__ ed2) {
    __shared__ float w2s[128 * 41];   // [k][41] pad: 4-way conflict max
    int tid = threadIdx.x;
    for (int i = tid; i < 128 * 40; i += 256) {
        int k = i / 40, c = i - k * 40;
        w2s[k * 41 + c] = W2[i];
    }
    __syncthreads();
    // grid is exactly NN*8/256 blocks; n < NN always
    int gid = blockIdx.x * 256 + tid;
    int n = gid >> 3;
    int l = tid & 7;
    float edn = ed1[n * 8 + l];
    int beg = rp[n], end = rp[n + 1];
    float acc[16];
    #pragma unroll
    for (int j = 0; j < 16; ++j) acc[j] = 0.f;
    float den = 0.f;
    int e = beg;
    int sA = col[e];
    int eB = (e + 1 < end) ? e + 1 : e;
    int sB = col[eB];
    float esA = es1[sA * 8 + l], esB = es1[sB * 8 + l];
    uint4 uA = h1v[sA * 8 + l];
    uint4 uB = h1v[sB * 8 + l];
    while (e < end) {
        int en = e + 2;
        int enA = (en < end) ? en : e;
        int enB = (en + 1 < end) ? en + 1 : enA;
        int nsA = col[enA], nsB = col[enB];
        float nesA = es1[nsA * 8 + l], nesB = es1[nsB * 8 + l];
        uint4 nuA = h1v[nsA * 8 + l];
        uint4 nuB = h1v[nsB * 8 + l];
        float exA = __expf(lrelu(esA + edn));
        float exB = (e + 1 < end) ? __expf(lrelu(esB + edn)) : 0.f;
        den += exA;
        den += exB;
        const unsigned* wA = (const unsigned*)&uA;
        const unsigned* wB = (const unsigned*)&uB;
        #pragma unroll
        for (int j = 0; j < 4; ++j) {
            f32x2 a01 = __builtin_amdgcn_cvt_pk_f32_fp8(wA[j], false);
            f32x2 a23 = __builtin_amdgcn_cvt_pk_f32_fp8(wA[j], true);
            f32x2 b01 = __builtin_amdgcn_cvt_pk_f32_fp8(wB[j], false);
            f32x2 b23 = __builtin_amdgcn_cvt_pk_f32_fp8(wB[j], true);
            acc[j * 4 + 0] += exA * a01.x; acc[j * 4 + 0] += exB * b01.x;
            acc[j * 4 + 1] += exA * a01.y; acc[j * 4 + 1] += exB * b01.y;
            acc[j * 4 + 2] += exA * a23.x; acc[j * 4 + 2] += exB * b23.x;
            acc[j * 4 + 3] += exA * a23.y; acc[j * 4 + 3] += exB * b23.y;
        }
        e = en;
        esA = nesA; esB = nesB;
        uA = nuA; uB = nuB;
    }
    float inv = 1.f / (den + 1e-16f);
    float row[16];
    #pragma unroll
    for (int i = 0; i < 4; ++i) {
        float4 b = ((const float4*)b1)[l * 4 + i];
        row[i * 4 + 0] = fmaxf(acc[i * 4 + 0] * inv + b.x, 0.f);
        row[i * 4 + 1] = fmaxf(acc[i * 4 + 1] * inv + b.y, 0.f);
        row[i * 4 + 2] = fmaxf(acc[i * 4 + 2] * inv + b.z, 0.f);
        row[i * 4 + 3] = fmaxf(acc[i * 4 + 3] * inv + b.w, 0.f);
    }
    // layer-2 GEMM partial: lane l owns k in [16l, 16l+16)
    float p[40];
    #pragma unroll
    for (int c = 0; c < 40; ++c) p[c] = 0.f;
    #pragma unroll
    for (int j = 0; j < 16; ++j) {
        float rv = row[j];
        const float* wr = &w2s[(l * 16 + j) * 41];
        #pragma unroll
        for (int c = 0; c < 40; ++c) p[c] += rv * wr[c];
    }
    #pragma unroll
    for (int o = 1; o <= 4; o <<= 1) {
        #pragma unroll
        for (int c = 0; c < 40; ++c) p[c] += __shfl_xor(p[c], o);
    }
    float s = 0.f, d = 0.f;
    #pragma unroll
    for (int c = 0; c < 40; ++c) { s += p[c] * as2[c]; d += p[c] * ad2[c]; }
    if (l == 0) { es2[n] = s; ed2[n] = d; }
    if (l < 5) {
        union { __half2 h[4]; uint4 u; } cv;
        #pragma unroll
        for (int i = 0; i < 4; ++i)
            cv.h[i] = __floats2half2_rn(p[l * 8 + i * 2], p[l * 8 + i * 2 + 1]);
        ((uint4*)h2h)[n * 5 + l] = cv.u;
    }
}

// -- Layer 2 aggregate + log_softmax: 8 lanes/node (5 active), fp16 h2, 2-edge unroll
__global__ void k_agg2(const int* __restrict__ rp, const int* __restrict__ col,
                       const uint4* __restrict__ h2v, const float* __restrict__ es2,
                       const float* __restrict__ ed2, const float* __restrict__ b2,
                       float* __restrict__ out) {
    int gid = blockIdx.x * blockDim.x + threadIdx.x;
    int n = gid >> 3;
    int l = threadIdx.x & 7;      // channel block l*8..l*8+7, active l<5
    if (n >= NN) return;
    bool qv = l < 5;
    float edn = ed2[n];
    int beg = rp[n], end = rp[n + 1];
    float acc[8];
    #pragma unroll
    for (int j = 0; j < 8; ++j) acc[j] = 0.f;
    float den = 0.f;
    int e = beg;
    int sA = col[e];
    int eB = (e + 1 < end) ? e + 1 : e;
    int sB = col[eB];
    float esA = es2[sA], esB = es2[sB];
    uint4 uA = qv ? h2v[sA * 5 + l] : make_uint4(0, 0, 0, 0);
    uint4 uB = qv ? h2v[sB * 5 + l] : make_uint4(0, 0, 0, 0);
    while (e < end) {
        int en = e + 2;
        int enA = (en < end) ? en : e;
        int enB = (en + 1 < end) ? en + 1 : enA;
        int nsA = col[enA], nsB = col[enB];
        float nesA = es2[nsA], nesB = es2[nsB];
        uint4 nuA = qv ? h2v[nsA * 5 + l] : make_uint4(0, 0, 0, 0);
        uint4 nuB = qv ? h2v[nsB * 5 + l] : make_uint4(0, 0, 0, 0);
        float exA = __expf(lrelu(esA + edn));
        float exB = (e + 1 < end) ? __expf(lrelu(esB + edn)) : 0.f;
        den += exA;
        den += exB;
        const __half2* pA = (const __half2*)&uA;
        const __half2* pB = (const __half2*)&uB;
        #pragma unroll
        for (int j = 0; j < 4; ++j) {
            float2 fA = __half22float2(pA[j]);
            float2 fB = __half22float2(pB[j]);
            acc[j * 2]     += exA * fA.x; acc[j * 2]     += exB * fB.x;
            acc[j * 2 + 1] += exA * fA.y; acc[j * 2 + 1] += exB * fB.y;
        }
        e = en;
        esA = nesA; esB = nesB;
        uA = nuA; uB = nuB;
    }
    float inv = 1.f / (den + 1e-16f);
    float v[8];
    float m = -INFINITY;
    if (qv) {
        #pragma unroll
        for (int j = 0; j < 8; ++j) {
            v[j] = acc[j] * inv + b2[l * 8 + j];
            m = fmaxf(m, v[j]);
        }
    }
    #pragma unroll
    for (int o = 1; o <= 4; o <<= 1) m = fmaxf(m, __shfl_xor(m, o));
    float es = 0.f;
    if (qv) {
        #pragma unroll
        for (int j = 0; j < 8; ++j) es += __expf(v[j] - m);
    }
    #pragma unroll
    for (int o = 1; o <= 4; o <<= 1) es += __shfl_xor(es, o);
    if (qv) {
        float ls = m + __logf(es);
        float4 o0, o1;
        o0.x = v[0] - ls; o0.y = v[1] - ls; o0.z = v[2] - ls; o0.w = v[3] - ls;
        o1.x = v[4] - ls; o1.y = v[5] - ls; o1.z = v[6] - ls; o1.w = v[7] - ls;
        ((float4*)out)[n * 10 + l * 2]     = o0;
        ((float4*)out)[n * 10 + l * 2 + 1] = o1;
    }
}

extern "C" void kernel_launch(void* const* d_in, const int* in_sizes, int n_in,
                              void* d_out, int out_size, void* d_ws, size_t ws_size,
                              hipStream_t stream) {
    const float* x   = (const float*)d_in[0];
    const int*   ei  = (const int*)d_in[1];   // int32 (JAX x64 disabled)
    const float* W1  = (const float*)d_in[2];
    const float* as1 = (const float*)d_in[3];
    const float* ad1 = (const float*)d_in[4];
    const float* b1  = (const float*)d_in[5];
    const float* W2  = (const float*)d_in[6];
    const float* as2 = (const float*)d_in[7];
    const float* ad2 = (const float*)d_in[8];
    const float* b2  = (const float*)d_in[9];
    float* out = (float*)d_out;

    const int* esrc = ei;
    const int* edst = ei + EE;

    // workspace layout
    unsigned* h1b = (unsigned*)d_ws;            // N*32 u32 = N*128 fp8 (12.8 MB)
    float* es1  = (float*)(h1b + NN * 32);      // N*8
    float* ed1  = es1 + NN * 8;                 // N*8
    __half* h2h = (__half*)(ed1 + NN * 8);      // N*40 fp16 (8 MB)
    float* es2  = (float*)(h2h + NN * 40);      // N
    float* ed2  = es2 + NN;                     // N
    int* rp     = (int*)(ed2 + NN);             // N+1
    int* col    = rp + NN + 1;                  // ET
    int* bcnt   = col + ET;                     // NBUCK
    int* bbase  = bcnt + NBUCK;                 // NBUCK+1
    int* bcur   = bbase + NBUCK + 1;            // NBUCK
    unsigned int* bedge = (unsigned int*)(bcur + NBUCK);  // ET
    __half* w1p = (__half*)(bedge + ET);        // 16384 fp16 (32 KB)

    // CSR build: bucket sort -> place (rp + sorted col)
    hipMemsetAsync(bcnt, 0, NBUCK * sizeof(int), stream);
    k_bhist<<<NAB, 256, 0, stream>>>(edst, bcnt);
    k_bscan<<<1, 256, 0, stream>>>(bcnt, bbase, bcur);
    k_bscatter<<<NAB, 256, 0, stream>>>(esrc, edst, bcur, bedge);
    k_place<<<NBUCK, 256, 0, stream>>>(bedge, bbase, rp, col);

    // layer 1 (MFMA gemm; fp8 h1)
    k_w1pack<<<64, 256, 0, stream>>>(W1, w1p);
    k_gemm1<<<(NN + 63) / 64, 256, 0, stream>>>(x, w1p, as1, ad1, h1b, es1, ed1);

    // agg1 fused with layer-2 GEMM + logits2 (out1 never materialized)
    k_agg1<<<(NN * 8) / 256, 256, 0, stream>>>(rp, col, (const uint4*)h1b, es1, ed1,
                                               b1, W2, as2, ad2, h2h, es2, ed2);

    // layer 2 aggregate + log_softmax
    k_agg2<<<(NN * 8 + 255) / 256, 256, 0, stream>>>(rp, col, (const uint4*)h2h, es2, ed2, b2, out);
}

// Round 20
// 240.725 us; speedup vs baseline: 1.3246x; 1.3246x over previous
//
#include <hip/hip_runtime.h>
#include <hip/hip_fp16.h>
#include <math.h>

#define NN 100000
#define EE 1600000
#define ET (EE + NN)
#define BWN 64        // nodes per bucket
#define NBUCK 1563    // ceil(NN/BWN)
#define ACHUNK 4096   // edges per bucket-scatter block
#define NAB 416       // ceil(ET/ACHUNK)
#define MAXS 1792     // LDS staging cap (mean 1088, sd ~33 -> +21 sigma)

typedef _Float16 f16x8 __attribute__((ext_vector_type(8)));
typedef float f32x4 __attribute__((ext_vector_type(4)));
typedef float f32x2 __attribute__((ext_vector_type(2)));

__device__ __forceinline__ float lrelu(float x) { return x > 0.f ? x : 0.2f * x; }

// ---- W1 fragment pack (single plane fp16) -----------------------------------------
__global__ void k_w1pack(const float* __restrict__ W1, __half* __restrict__ w1p) {
    int idx = blockIdx.x * 256 + threadIdx.x;   // 0..16383
    int j = idx & 7, lane = (idx >> 3) & 63, k0 = (idx >> 9) & 3;
    int ct = (idx >> 11) & 7;
    int k = k0 * 32 + (lane >> 4) * 8 + j;
    int c = ct * 16 + (lane & 15);
    _Float16 v = (_Float16)W1[k * 128 + c];
    w1p[idx] = *(__half*)&v;
}

// ---- W2 fragment pack: [ct:3][k0:4][lane:64][j:8], cols >= 40 zero-padded ---------
__global__ void k_w2pack(const float* __restrict__ W2, __half* __restrict__ w2p) {
    int idx = blockIdx.x * 256 + threadIdx.x;   // 0..6143
    int j = idx & 7, lane = (idx >> 3) & 63, k0 = (idx >> 9) & 3;
    int ct = idx >> 11;                          // 0..2
    int k = k0 * 32 + (lane >> 4) * 8 + j;
    int c = ct * 16 + (lane & 15);
    _Float16 v = (_Float16)((c < 40) ? W2[k * 40 + c] : 0.f);
    w2p[idx] = *(__half*)&v;
}

// ---- Layer 1 GEMM via MFMA (fp16), swapped operands; fp8 h1; es/ed from fp32 acc --
__global__ __launch_bounds__(256) void k_gemm1(
        const float* __restrict__ x, const __half* __restrict__ w1p,
        const float* __restrict__ as1, const float* __restrict__ ad1,
        unsigned* __restrict__ h1b, float* __restrict__ es1, float* __restrict__ ed1) {
    int tid = threadIdx.x;
    int w = tid >> 6, lane = tid & 63;
    int rb = blockIdx.x * 64 + w * 16;
    int l15 = lane & 15, rg = lane >> 4;

    int arow = rb + l15;
    bool aok = arow < NN;
    const float4* x4 = (const float4*)x;
    f16x8 ah[4];
    #pragma unroll
    for (int k0 = 0; k0 < 4; ++k0) {
        float4 p0 = make_float4(0.f, 0.f, 0.f, 0.f), p1 = p0;
        if (aok) {
            int fi = arow * 32 + k0 * 8 + rg * 2;
            p0 = x4[fi];
            p1 = x4[fi + 1];
        }
        float pv[8] = {p0.x, p0.y, p0.z, p0.w, p1.x, p1.y, p1.z, p1.w};
        #pragma unroll
        for (int j = 0; j < 8; ++j) ah[k0][j] = (_Float16)pv[j];
    }

    const f16x8* w1f = (const f16x8*)w1p;   // [ct:8][k0:4][lane:64]
    f32x4 acc[8];
    #pragma unroll
    for (int ct = 0; ct < 8; ++ct) acc[ct] = (f32x4){0.f, 0.f, 0.f, 0.f};
    #pragma unroll
    for (int ct = 0; ct < 8; ++ct) {
        #pragma unroll
        for (int k0 = 0; k0 < 4; ++k0) {
            f16x8 bh = w1f[(ct * 4 + k0) * 64 + lane];
            acc[ct] = __builtin_amdgcn_mfma_f32_16x16x32_f16(bh, ah[k0], acc[ct], 0, 0, 0);
        }
    }

    int row = rb + l15;
    bool rok = row < NN;
    #pragma unroll
    for (int ct = 0; ct < 8; ++ct) {
        if (rok) {
            unsigned pw = __builtin_amdgcn_cvt_pk_fp8_f32(acc[ct][0], acc[ct][1], 0u, false);
            pw = __builtin_amdgcn_cvt_pk_fp8_f32(acc[ct][2], acc[ct][3], pw, true);
            h1b[row * 32 + ct * 4 + rg] = pw;
        }
        float4 a4 = ((const float4*)as1)[ct * 4 + rg];
        float4 d4 = ((const float4*)ad1)[ct * 4 + rg];
        float s = acc[ct][0] * a4.x + acc[ct][1] * a4.y + acc[ct][2] * a4.z + acc[ct][3] * a4.w;
        float d = acc[ct][0] * d4.x + acc[ct][1] * d4.y + acc[ct][2] * d4.z + acc[ct][3] * d4.w;
        s += __shfl_xor(s, 16); s += __shfl_xor(s, 32);
        d += __shfl_xor(d, 16); d += __shfl_xor(d, 32);
        if (rg == 0 && rok) { es1[row * 8 + ct] = s; ed1[row * 8 + ct] = d; }
    }
}

// ================= CSR build: two-level bucket sort (write-amp-free) ===============
__global__ void k_bhist(const int* __restrict__ dst, int* __restrict__ bcnt) {
    __shared__ int lh[NBUCK];
    int t = threadIdx.x;
    for (int i = t; i < NBUCK; i += 256) lh[i] = 0;
    __syncthreads();
    int c0 = blockIdx.x * ACHUNK;
    #pragma unroll
    for (int i = 0; i < 16; ++i) {
        int e = c0 + t + i * 256;
        if (e < ET) {
            int d = (e < EE) ? dst[e] : e - EE;
            atomicAdd(&lh[d >> 6], 1);
        }
    }
    __syncthreads();
    for (int i = t; i < NBUCK; i += 256) {
        int c = lh[i];
        if (c) atomicAdd(&bcnt[i], c);
    }
}

// single block, 8 buckets per thread (2048 >= NBUCK+1)
__global__ void k_bscan(const int* __restrict__ bcnt, int* __restrict__ bbase,
                        int* __restrict__ bcur) {
    __shared__ int sd[256];
    int t = threadIdx.x;
    int base = t * 8;
    int v[8];
    int s = 0;
    #pragma unroll
    for (int j = 0; j < 8; ++j) {
        int i = base + j;
        v[j] = (i < NBUCK) ? bcnt[i] : 0;
        s += v[j];
    }
    sd[t] = s;
    __syncthreads();
    for (int off = 1; off < 256; off <<= 1) {
        int x = (t >= off) ? sd[t - off] : 0;
        __syncthreads();
        sd[t] += x;
        __syncthreads();
    }
    int excl = sd[t] - s;
    #pragma unroll
    for (int j = 0; j < 8; ++j) {
        int i = base + j;
        if (i <= NBUCK) { bbase[i] = excl; if (i < NBUCK) bcur[i] = excl; }
        excl += v[j];
    }
}

__global__ void k_bscatter(const int* __restrict__ src, const int* __restrict__ dst,
                           int* __restrict__ bcur, unsigned int* __restrict__ bedge) {
    __shared__ int lh[NBUCK];
    __shared__ int lb[NBUCK];
    int t = threadIdx.x;
    for (int i = t; i < NBUCK; i += 256) lh[i] = 0;
    __syncthreads();
    int c0 = blockIdx.x * ACHUNK;
    unsigned int val[16];
    int bkt[16];
    int rnk[16];
    #pragma unroll
    for (int i = 0; i < 16; ++i) {
        int e = c0 + t + i * 256;
        if (e < ET) {
            int s, d;
            if (e < EE) { s = src[e]; d = dst[e]; } else { s = d = e - EE; }
            int b = d >> 6;
            bkt[i] = b;
            val[i] = (unsigned)s | ((unsigned)(d & 63) << 24);
            rnk[i] = atomicAdd(&lh[b], 1);
        } else bkt[i] = -1;
    }
    __syncthreads();
    for (int i = t; i < NBUCK; i += 256) {
        int c = lh[i];
        lb[i] = c ? atomicAdd(&bcur[i], c) : 0;
    }
    __syncthreads();
    #pragma unroll
    for (int i = 0; i < 16; ++i)
        if (bkt[i] >= 0) bedge[lb[bkt[i]] + rnk[i]] = val[i];
}

// --- Fused: rp (wave-shfl scan); place + per-node value sort (determinism) +
//     coalesced col write. 64-node buckets. --------------------------------------
__global__ void k_place(const unsigned int* __restrict__ bedge,
                        const int* __restrict__ bbase, int* __restrict__ rp,
                        int* __restrict__ col) {
    __shared__ int lh[BWN];
    __shared__ int ex[BWN + 1];
    __shared__ int lcur[BWN];
    __shared__ int stg[MAXS];
    int b = blockIdx.x, t = threadIdx.x;
    int beg = bbase[b], end = bbase[b + 1];
    if (t < BWN) { lh[t] = 0; lcur[t] = 0; }
    __syncthreads();
    for (int e = beg + t; e < end; e += 256) atomicAdd(&lh[(bedge[e] >> 24) & 63], 1);
    __syncthreads();
    if (t < 64) {
        int v = lh[t];
        int x = v;
        #pragma unroll
        for (int off = 1; off < 64; off <<= 1) {
            int y = __shfl_up(x, off);
            if (t >= off) x += y;
        }
        ex[t] = x - v;
        if (t == 63) ex[64] = x;
    }
    __syncthreads();
    int n = b * BWN + t;
    if (t < BWN && n < NN) rp[n] = beg + ex[t];
    if (b == 0 && t == 0) rp[NN] = ET;
    int S = ex[BWN];
    int lane = t & 63, w = t >> 6;
    if (S <= MAXS) {
        for (int e = beg + t; e < end; e += 256) {
            unsigned u = bedge[e];
            int i = (u >> 24) & 63;
            int pos = ex[i] + atomicAdd(&lcur[i], 1);
            stg[pos] = (int)(u & 0xFFFFFFu);
        }
        __syncthreads();
        for (int i = w; i < BWN; i += 4) {
            int sb = ex[i], d = lh[i];
            if (d <= 1) continue;
            if (d <= 64) {
                int vv = (lane < d) ? stg[sb + lane] : 0x7fffffff;
                #pragma unroll
                for (int k = 2; k <= 64; k <<= 1) {
                    #pragma unroll
                    for (int j = k >> 1; j > 0; j >>= 1) {
                        int other = __shfl_xor(vv, j);
                        bool lower = (lane & j) == 0;
                        bool up = (lane & k) == 0;
                        vv = (lower == up) ? min(vv, other) : max(vv, other);
                    }
                }
                if (lane < d) stg[sb + lane] = vv;
            } else if (lane == 0) {
                for (int p = sb + 1; p < sb + d; ++p) {
                    int key = stg[p]; int j = p - 1;
                    while (j >= sb && stg[j] > key) { stg[j + 1] = stg[j]; --j; }
                    stg[j + 1] = key;
                }
            }
        }
        __syncthreads();
        for (int j = t; j < S; j += 256) col[beg + j] = stg[j];
    } else {
        for (int e = beg + t; e < end; e += 256) {
            unsigned u = bedge[e];
            int i = (u >> 24) & 63;
            int pos = beg + ex[i] + atomicAdd(&lcur[i], 1);
            col[pos] = (int)(u & 0xFFFFFFu);
        }
        __syncthreads();
        if (t < BWN) {
            int sb = beg + ex[t], d = lh[t];
            for (int p = sb + 1; p < sb + d; ++p) {
                int key = col[p]; int j = p - 1;
                while (j >= sb && col[j] > key) { col[j + 1] = col[j]; --j; }
                col[j + 1] = key;
            }
        }
    }
}

// --- Layer 1 aggregate: 8 lanes/node, fp8 h1, 2-edge unroll; out1 fp16 -------------
__global__ void k_agg1(const int* __restrict__ rp, const int* __restrict__ col,
                       const uint4* __restrict__ h1v, const float* __restrict__ es1,
                       const float* __restrict__ ed1, const float* __restrict__ b1,
                       __half* __restrict__ out1h) {
    int gid = blockIdx.x * blockDim.x + threadIdx.x;
    int n = gid >> 3;
    int l = threadIdx.x & 7;
    if (n >= NN) return;
    float edn = ed1[n * 8 + l];
    int beg = rp[n], end = rp[n + 1];
    float acc[16];
    #pragma unroll
    for (int j = 0; j < 16; ++j) acc[j] = 0.f;
    float den = 0.f;
    int e = beg;
    int sA = col[e];
    int eB = (e + 1 < end) ? e + 1 : e;
    int sB = col[eB];
    float esA = es1[sA * 8 + l], esB = es1[sB * 8 + l];
    uint4 uA = h1v[sA * 8 + l];
    uint4 uB = h1v[sB * 8 + l];
    while (e < end) {
        int en = e + 2;
        int enA = (en < end) ? en : e;
        int enB = (en + 1 < end) ? en + 1 : enA;
        int nsA = col[enA], nsB = col[enB];
        float nesA = es1[nsA * 8 + l], nesB = es1[nsB * 8 + l];
        uint4 nuA = h1v[nsA * 8 + l];
        uint4 nuB = h1v[nsB * 8 + l];
        float exA = __expf(lrelu(esA + edn));
        float exB = (e + 1 < end) ? __expf(lrelu(esB + edn)) : 0.f;
        den += exA;
        den += exB;
        const unsigned* wA = (const unsigned*)&uA;
        const unsigned* wB = (const unsigned*)&uB;
        #pragma unroll
        for (int j = 0; j < 4; ++j) {
            f32x2 a01 = __builtin_amdgcn_cvt_pk_f32_fp8(wA[j], false);
            f32x2 a23 = __builtin_amdgcn_cvt_pk_f32_fp8(wA[j], true);
            f32x2 b01 = __builtin_amdgcn_cvt_pk_f32_fp8(wB[j], false);
            f32x2 b23 = __builtin_amdgcn_cvt_pk_f32_fp8(wB[j], true);
            acc[j * 4 + 0] += exA * a01.x; acc[j * 4 + 0] += exB * b01.x;
            acc[j * 4 + 1] += exA * a01.y; acc[j * 4 + 1] += exB * b01.y;
            acc[j * 4 + 2] += exA * a23.x; acc[j * 4 + 2] += exB * b23.x;
            acc[j * 4 + 3] += exA * a23.y; acc[j * 4 + 3] += exB * b23.y;
        }
        e = en;
        esA = nesA; esB = nesB;
        uA = nuA; uB = nuB;
    }
    float inv = 1.f / (den + 1e-16f);
    union { __half2 h[8]; uint4 u[2]; } cv;
    #pragma unroll
    for (int i = 0; i < 4; ++i) {
        float4 b = ((const float4*)b1)[l * 4 + i];
        float o0 = fmaxf(acc[i * 4]     * inv + b.x, 0.f);
        float o1 = fmaxf(acc[i * 4 + 1] * inv + b.y, 0.f);
        float o2 = fmaxf(acc[i * 4 + 2] * inv + b.z, 0.f);
        float o3 = fmaxf(acc[i * 4 + 3] * inv + b.w, 0.f);
        cv.h[i * 2]     = __floats2half2_rn(o0, o1);
        cv.h[i * 2 + 1] = __floats2half2_rn(o2, o3);
    }
    // row = 128 halves = 16 uint4
    ((uint4*)out1h)[n * 16 + l * 2]     = cv.u[0];
    ((uint4*)out1h)[n * 16 + l * 2 + 1] = cv.u[1];
}

// ---- Layer 2 GEMM via MFMA (fp16), swapped operands; fused logits; fp16 h2 --------
// Wave = 16 rows x 48 cols (3 ct tiles; cols >= 40 zero in w2p). No LDS.
__global__ __launch_bounds__(256) void k_gemm2(
        const __half* __restrict__ out1h, const __half* __restrict__ w2p,
        const float* __restrict__ as2, const float* __restrict__ ad2,
        __half* __restrict__ h2h, float* __restrict__ es2, float* __restrict__ ed2) {
    int tid = threadIdx.x;
    int w = tid >> 6, lane = tid & 63;
    int rb = blockIdx.x * 64 + w * 16;
    int l15 = lane & 15, rg = lane >> 4;

    int arow = rb + l15;
    bool aok = arow < NN;
    f16x8 af[4];
    #pragma unroll
    for (int k0 = 0; k0 < 4; ++k0) {
        uint4 u = make_uint4(0, 0, 0, 0);
        if (aok) u = ((const uint4*)out1h)[arow * 16 + k0 * 4 + rg];
        af[k0] = *(f16x8*)&u;
    }

    const f16x8* w2f = (const f16x8*)w2p;   // [ct:3][k0:4][lane:64]
    int row = rb + l15;
    bool rok = row < NN;
    float sacc = 0.f, dacc = 0.f;
    #pragma unroll
    for (int ct = 0; ct < 3; ++ct) {
        f32x4 acc = (f32x4){0.f, 0.f, 0.f, 0.f};
        #pragma unroll
        for (int k0 = 0; k0 < 4; ++k0) {
            f16x8 bh = w2f[(ct * 4 + k0) * 64 + lane];
            acc = __builtin_amdgcn_mfma_f32_16x16x32_f16(bh, af[k0], acc, 0, 0, 0);
        }
        int cbase = ct * 16 + rg * 4;
        if (cbase < 40) {
            float4 a4 = ((const float4*)as2)[ct * 4 + rg];
            float4 d4 = ((const float4*)ad2)[ct * 4 + rg];
            sacc += acc[0] * a4.x + acc[1] * a4.y + acc[2] * a4.z + acc[3] * a4.w;
            dacc += acc[0] * d4.x + acc[1] * d4.y + acc[2] * d4.z + acc[3] * d4.w;
            if (rok) {
                union { __half2 h[2]; uint2 u; } cv;
                cv.h[0] = __floats2half2_rn(acc[0], acc[1]);
                cv.h[1] = __floats2half2_rn(acc[2], acc[3]);
                *(uint2*)&h2h[row * 40 + cbase] = cv.u;
            }
        }
    }
    sacc += __shfl_xor(sacc, 16); sacc += __shfl_xor(sacc, 32);
    dacc += __shfl_xor(dacc, 16); dacc += __shfl_xor(dacc, 32);
    if (rg == 0 && rok) { es2[row] = sacc; ed2[row] = dacc; }
}

// -- Layer 2 aggregate + log_softmax: 8 lanes/node (5 active), fp16 h2, 2-edge unroll
__global__ void k_agg2(const int* __restrict__ rp, const int* __restrict__ col,
                       const uint4* __restrict__ h2v, const float* __restrict__ es2,
                       const float* __restrict__ ed2, const float* __restrict__ b2,
                       float* __restrict__ out) {
    int gid = blockIdx.x * blockDim.x + threadIdx.x;
    int n = gid >> 3;
    int l = threadIdx.x & 7;      // channel block l*8..l*8+7, active l<5
    if (n >= NN) return;
    bool qv = l < 5;
    float edn = ed2[n];
    int beg = rp[n], end = rp[n + 1];
    float acc[8];
    #pragma unroll
    for (int j = 0; j < 8; ++j) acc[j] = 0.f;
    float den = 0.f;
    int e = beg;
    int sA = col[e];
    int eB = (e + 1 < end) ? e + 1 : e;
    int sB = col[eB];
    float esA = es2[sA], esB = es2[sB];
    uint4 uA = qv ? h2v[sA * 5 + l] : make_uint4(0, 0, 0, 0);
    uint4 uB = qv ? h2v[sB * 5 + l] : make_uint4(0, 0, 0, 0);
    while (e < end) {
        int en = e + 2;
        int enA = (en < end) ? en : e;
        int enB = (en + 1 < end) ? en + 1 : enA;
        int nsA = col[enA], nsB = col[enB];
        float nesA = es2[nsA], nesB = es2[nsB];
        uint4 nuA = qv ? h2v[nsA * 5 + l] : make_uint4(0, 0, 0, 0);
        uint4 nuB = qv ? h2v[nsB * 5 + l] : make_uint4(0, 0, 0, 0);
        float exA = __expf(lrelu(esA + edn));
        float exB = (e + 1 < end) ? __expf(lrelu(esB + edn)) : 0.f;
        den += exA;
        den += exB;
        const __half2* pA = (const __half2*)&uA;
        const __half2* pB = (const __half2*)&uB;
        #pragma unroll
        for (int j = 0; j < 4; ++j) {
            float2 fA = __half22float2(pA[j]);
            float2 fB = __half22float2(pB[j]);
            acc[j * 2]     += exA * fA.x; acc[j * 2]     += exB * fB.x;
            acc[j * 2 + 1] += exA * fA.y; acc[j * 2 + 1] += exB * fB.y;
        }
        e = en;
        esA = nesA; esB = nesB;
        uA = nuA; uB = nuB;
    }
    float inv = 1.f / (den + 1e-16f);
    float v[8];
    float m = -INFINITY;
    if (qv) {
        #pragma unroll
        for (int j = 0; j < 8; ++j) {
            v[j] = acc[j] * inv + b2[l * 8 + j];
            m = fmaxf(m, v[j]);
        }
    }
    #pragma unroll
    for (int o = 1; o <= 4; o <<= 1) m = fmaxf(m, __shfl_xor(m, o));
    float es = 0.f;
    if (qv) {
        #pragma unroll
        for (int j = 0; j < 8; ++j) es += __expf(v[j] - m);
    }
    #pragma unroll
    for (int o = 1; o <= 4; o <<= 1) es += __shfl_xor(es, o);
    if (qv) {
        float ls = m + __logf(es);
        float4 o0, o1;
        o0.x = v[0] - ls; o0.y = v[1] - ls; o0.z = v[2] - ls; o0.w = v[3] - ls;
        o1.x = v[4] - ls; o1.y = v[5] - ls; o1.z = v[6] - ls; o1.w = v[7] - ls;
        ((float4*)out)[n * 10 + l * 2]     = o0;
        ((float4*)out)[n * 10 + l * 2 + 1] = o1;
    }
}

extern "C" void kernel_launch(void* const* d_in, const int* in_sizes, int n_in,
                              void* d_out, int out_size, void* d_ws, size_t ws_size,
                              hipStream_t stream) {
    const float* x   = (const float*)d_in[0];
    const int*   ei  = (const int*)d_in[1];   // int32 (JAX x64 disabled)
    const float* W1  = (const float*)d_in[2];
    const float* as1 = (const float*)d_in[3];
    const float* ad1 = (const float*)d_in[4];
    const float* b1  = (const float*)d_in[5];
    const float* W2  = (const float*)d_in[6];
    const float* as2 = (const float*)d_in[7];
    const float* ad2 = (const float*)d_in[8];
    const float* b2  = (const float*)d_in[9];
    float* out = (float*)d_out;

    const int* esrc = ei;
    const int* edst = ei + EE;

    // workspace layout
    unsigned* h1b = (unsigned*)d_ws;            // N*32 u32 = N*128 fp8 (12.8 MB)
    float* es1  = (float*)(h1b + NN * 32);      // N*8
    float* ed1  = es1 + NN * 8;                 // N*8
    __half* out1h = (__half*)(ed1 + NN * 8);    // N*128 fp16 (25.6 MB)
    __half* h2h = out1h + NN * 128;             // N*40 fp16 (8 MB)
    float* es2  = (float*)(h2h + NN * 40);      // N
    float* ed2  = es2 + NN;                     // N
    int* rp     = (int*)(ed2 + NN);             // N+1
    int* col    = rp + NN + 1;                  // ET
    int* bcnt   = col + ET;                     // NBUCK
    int* bbase  = bcnt + NBUCK;                 // NBUCK+1
    int* bcur   = bbase + NBUCK + 1;            // NBUCK
    unsigned int* bedge = (unsigned int*)(bcur + NBUCK);  // ET
    __half* w1p = (__half*)(bedge + ET);        // 16384 fp16 (32 KB)
    __half* w2p = w1p + 16384;                  // 6144 fp16 (12 KB)

    // CSR build: bucket sort -> place (rp + sorted col)
    hipMemsetAsync(bcnt, 0, NBUCK * sizeof(int), stream);
    k_bhist<<<NAB, 256, 0, stream>>>(edst, bcnt);
    k_bscan<<<1, 256, 0, stream>>>(bcnt, bbase, bcur);
    k_bscatter<<<NAB, 256, 0, stream>>>(esrc, edst, bcur, bedge);
    k_place<<<NBUCK, 256, 0, stream>>>(bedge, bbase, rp, col);

    // layer 1 (MFMA gemm; fp8 h1, fp16 out1)
    k_w1pack<<<64, 256, 0, stream>>>(W1, w1p);
    k_gemm1<<<(NN + 63) / 64, 256, 0, stream>>>(x, w1p, as1, ad1, h1b, es1, ed1);
    k_agg1<<<(NN * 8 + 255) / 256, 256, 0, stream>>>(rp, col, (const uint4*)h1b, es1, ed1, b1, out1h);

    // layer 2 (MFMA gemm fused with logits; fp16 h2)
    k_w2pack<<<24, 256, 0, stream>>>(W2, w2p);
    k_gemm2<<<(NN + 63) / 64, 256, 0, stream>>>(out1h, w2p, as2, ad2, h2h, es2, ed2);
    k_agg2<<<(NN * 8 + 255) / 256, 256, 0, stream>>>(rp, col, (const uint4*)h2h, es2, ed2, b2, out);
}